// Round 5
// baseline (39.593 us; speedup 1.0000x reference)
//
#include <hip/hip_runtime.h>
#include <hip/hip_bf16.h>

#define TOKENS 16384
#define NEXP 8
#define INF 512
#define OUTF 512

#define BM 128
#define BN 128
#define BK 32
#define NS (INF / BK)      // 16 K-steps
#define MAXMT 40           // counts ~2048±42(σ); 5120 rows = +73σ
#define EROWS (MAXMT * BM) // 5120 rows per expert region

using f32x4 = __attribute__((ext_vector_type(4))) float;
using bfrag = __attribute__((ext_vector_type(8))) __bf16;
using s8v   = __attribute__((ext_vector_type(8))) short;

// fp32 -> bf16 RNE
__device__ __forceinline__ short f2bf(float f) {
  union { float f; unsigned u; } v; v.f = f;
  unsigned r = v.u + 0x7fffu + ((v.u >> 16) & 1u);
  return (short)(r >> 16);
}

__device__ __forceinline__ void gload16(const void* g, void* l) {
  __builtin_amdgcn_global_load_lds(
      (const __attribute__((address_space(1))) unsigned int*)g,
      (__attribute__((address_space(3))) unsigned int*)l, 16, 0, 0);
}

__device__ __forceinline__ s8v pack8(float4 a, float4 b) {
  s8v p;
  p[0] = f2bf(a.x); p[1] = f2bf(a.y); p[2] = f2bf(a.z); p[3] = f2bf(a.w);
  p[4] = f2bf(b.x); p[5] = f2bf(b.y); p[6] = f2bf(b.z); p[7] = f2bf(b.w);
  return p;
}

// weight fp32 -> bf16 [E][O][I]; also zeroes the scatter cursor
__global__ void k_convw(const float* __restrict__ w, s8v* __restrict__ wb,
                        int* __restrict__ cursor) {
  if (blockIdx.x == 0 && threadIdx.x < NEXP) cursor[threadIdx.x] = 0;
  int idx = blockIdx.x * 256 + threadIdx.x;
  const float4* src = (const float4*)w + (size_t)idx * 2;
  wb[idx] = pack8(src[0], src[1]);
}

// Bucket tokens by expert; emit perm[slot]=t and inv[t]=slot.
__global__ void k_scatter(const int* __restrict__ gate, int* __restrict__ cursor,
                          int* __restrict__ perm, int* __restrict__ inv) {
  __shared__ int lc[NEXP], lb[NEXP];
  int tid = threadIdx.x;
  if (tid < NEXP) lc[tid] = 0;
  __syncthreads();
  int t = blockIdx.x * 256 + tid;
  int e = gate[t];
  int ls = atomicAdd(&lc[e], 1);
  __syncthreads();
  if (tid < NEXP) lb[tid] = lc[tid] ? atomicAdd(&cursor[tid], lc[tid]) : 0;
  __syncthreads();
  int slot = e * EROWS + lb[e] + ls;
  perm[slot] = t;
  inv[t] = slot;
}

// Streaming gather+convert: Xg[slot] = bf16(inp[t]); barrier-free, fill-like.
// 2048 blocks x 256 thr; 8 tokens/block, 32 lanes/row, 64B read 32B write /lane.
__global__ void k_gather(const float* __restrict__ inp, const int* __restrict__ inv,
                         short* __restrict__ Xg) {
  int t = blockIdx.x * 8 + (threadIdx.x >> 5);
  int l = threadIdx.x & 31;
  int slot = inv[t];
  const float4* src = (const float4*)(inp + (size_t)t * INF) + l * 4;
  float4 a = src[0], b = src[1], c = src[2], d = src[3];
  s8v* dst = (s8v*)(Xg + (size_t)slot * INF + l * 16);
  dst[0] = pack8(a, b);
  dst[1] = pack8(c, d);
}

#define BARRIER4                                                        \
  asm volatile("s_waitcnt vmcnt(4) lgkmcnt(0)" ::: "memory");           \
  __builtin_amdgcn_sched_barrier(0);                                    \
  __builtin_amdgcn_s_barrier();                                         \
  __builtin_amdgcn_sched_barrier(0);
#define BARRIER0                                                        \
  asm volatile("s_waitcnt vmcnt(0) lgkmcnt(0)" ::: "memory");           \
  __builtin_amdgcn_sched_barrier(0);                                    \
  __builtin_amdgcn_s_barrier();                                         \
  __builtin_amdgcn_sched_barrier(0);

// Grouped GEMM, all-DMA staging, BK=32, 3-deep LDS ring, counted-vmcnt
// barriers (T4): DMA(t+2) rides across every barrier; zero per-step drain.
// XCD-affine grid: e=bid&7 -> XCD e; nt siblings 8 apart share A panel in L2.
__global__ __launch_bounds__(256, 4)
void moe_gemm2(const short* __restrict__ Xg, const short* __restrict__ wbf,
               const int* __restrict__ cursor, const int* __restrict__ perm,
               float* __restrict__ out) {
  const int bid = blockIdx.x;
  const int e  = bid & 7;
  const int nt = (bid >> 3) & 3;
  const int mt = bid >> 5;
  const int cnt = cursor[e];
  if (mt * BM >= cnt) return;
  const int m_valid = min(BM, cnt - mt * BM);

  __shared__ __align__(16) short As[3][BM * BK];  // 3 x 8 KB ring
  __shared__ __align__(16) short Bs[3][BN * BK];  // 3 x 8 KB ring
  __shared__ int toks[BM];

  const int tid = threadIdx.x;
  if (tid < BM) toks[tid] = perm[e * EROWS + mt * BM + tid];

  const int lane = tid & 63;
  const int wid  = tid >> 6;
  const int wr = wid >> 1, wc = wid & 1;
  const int lr = lane & 15;
  const int lg = lane >> 4;

  // DMA geometry: site s in {0,1}; chunk = s*256+tid; row=chunk>>2; c=chunk&3;
  // source pre-swizzled clog = c ^ ((row>>1)&3); LDS dest linear (rule #21).
  const short* Xbase = Xg  + ((size_t)e * EROWS + (size_t)mt * BM) * INF;
  const short* Wbase = wbf + ((size_t)e * OUTF + (size_t)nt * BN) * INF;
  const short* agp[2];
  const short* bgp[2];
  int ldst[2];
#pragma unroll
  for (int s = 0; s < 2; s++) {
    int chunk = s * 256 + tid;
    int row = chunk >> 2, c = chunk & 3;
    int clog = c ^ ((row >> 1) & 3);
    agp[s] = Xbase + (size_t)row * INF + clog * 8;
    bgp[s] = Wbase + (size_t)row * INF + clog * 8;
    ldst[s] = s * 4096 + wid * 1024;
  }

  // fragment LDS byte-offsets (swizzled read side)
  int aoff[4], boff[4];
#pragma unroll
  for (int i = 0; i < 4; i++) {
    int ra = wr * 64 + i * 16 + lr;
    int rb = wc * 64 + i * 16 + lr;
    aoff[i] = ra * 64 + ((lg ^ ((ra >> 1) & 3)) << 4);
    boff[i] = rb * 64 + ((lg ^ ((rb >> 1) & 3)) << 4);
  }

  f32x4 acc[4][4];
#pragma unroll
  for (int i = 0; i < 4; i++)
#pragma unroll
    for (int j = 0; j < 4; j++) acc[i][j] = (f32x4)0.0f;

#define DMA(t)                                                                \
  {                                                                           \
    const int kk_ = (t) * BK;                                                 \
    char* ab_ = (char*)&As[(t) % 3][0];                                       \
    char* bb_ = (char*)&Bs[(t) % 3][0];                                       \
    gload16(agp[0] + kk_, ab_ + ldst[0]);                                     \
    gload16(agp[1] + kk_, ab_ + ldst[1]);                                     \
    gload16(bgp[0] + kk_, bb_ + ldst[0]);                                     \
    gload16(bgp[1] + kk_, bb_ + ldst[1]);                                     \
  }
#define COMPUTE(t)                                                            \
  {                                                                           \
    const char* ab_ = (const char*)&As[(t) % 3][0];                           \
    const char* bb_ = (const char*)&Bs[(t) % 3][0];                           \
    bfrag af[4];                                                              \
    _Pragma("unroll") for (int i = 0; i < 4; i++)                             \
        af[i] = *(const bfrag*)(ab_ + aoff[i]);                               \
    _Pragma("unroll") for (int j = 0; j < 4; j++) {                           \
      bfrag bv = *(const bfrag*)(bb_ + boff[j]);                              \
      _Pragma("unroll") for (int i = 0; i < 4; i++)                           \
          acc[i][j] = __builtin_amdgcn_mfma_f32_16x16x32_bf16(af[i], bv,      \
                                                              acc[i][j],     \
                                                              0, 0, 0);      \
    }                                                                         \
  }

  // prologue: fill ring slots 0,1; wait slot 0 (retire oldest 4 of 8)
  DMA(0);
  DMA(1);
  BARRIER4;

  for (int t = 0; t < NS - 2; t++) {
    DMA(t + 2);        // rides across the barrier (counted vmcnt)
    COMPUTE(t);
    BARRIER4;          // retires DMA(t+1); DMA(t+2) stays in flight
  }
  COMPUTE(NS - 2);
  BARRIER0;            // drain DMA(NS-1)
  COMPUTE(NS - 1);

  // epilogue: C/D col=lane&15, row=(lane>>4)*4+reg
#pragma unroll
  for (int i = 0; i < 4; i++) {
    int rbase = wr * 64 + i * 16 + lg * 4;
#pragma unroll
    for (int r = 0; r < 4; r++) {
      int rr = rbase + r;
      if (rr < m_valid) {
        float* orow = out + (size_t)toks[rr] * OUTF + nt * BN + wc * 64 + lr;
#pragma unroll
        for (int j = 0; j < 4; j++) orow[j * 16] = acc[i][j][r];
      }
    }
  }
#undef DMA
#undef COMPUTE
}

extern "C" void kernel_launch(void* const* d_in, const int* in_sizes, int n_in,
                              void* d_out, int out_size, void* d_ws, size_t ws_size,
                              hipStream_t stream) {
  (void)in_sizes; (void)n_in; (void)out_size; (void)ws_size;
  const float* inp    = (const float*)d_in[0];
  const int*   gate   = (const int*)d_in[1];
  const float* weight = (const float*)d_in[2];
  float* out = (float*)d_out;

  char* ws = (char*)d_ws;
  int*   cursor = (int*)ws;                    // 64 B
  int*   perm   = (int*)(ws + 4096);           // 8*5120*4 = 160 KB
  int*   inv    = (int*)(ws + (256 << 10));    // 64 KB
  short* wbf    = (short*)(ws + (1 << 20));    // 4 MB bf16 weight
  short* Xg     = (short*)(ws + (8 << 20));    // 8*5120*512*2 = 40 MB

  k_convw<<<(NEXP * OUTF * INF) / (256 * 8), 256, 0, stream>>>(weight, (s8v*)wbf,
                                                               cursor);
  k_scatter<<<TOKENS / 256, 256, 0, stream>>>(gate, cursor, perm, inv);
  k_gather<<<TOKENS / 8, 256, 0, stream>>>(inp, inv, Xg);
  moe_gemm2<<<NEXP * 4 * MAXMT, 256, 0, stream>>>(Xg, wbf, cursor, perm, out);
}

// Round 8
// 39.578 us; speedup vs baseline: 1.0004x; 1.0004x over previous
//
#include <hip/hip_runtime.h>
#include <hip/hip_bf16.h>

#define TOKENS 16384
#define NEXP 8
#define INF 512
#define OUTF 512

#define BM 128
#define BN 128
#define BK 32
#define NS (INF / BK)      // 16 K-steps
#define MAXMT 40           // counts ~2048±42(σ); 5120 rows = +73σ
#define EROWS (MAXMT * BM)
#define SLOT 24576         // 16 KB fp32 A + 8 KB bf16 B per ring slot

using f32x4 = __attribute__((ext_vector_type(4))) float;
using bfrag = __attribute__((ext_vector_type(8))) __bf16;
using s8v   = __attribute__((ext_vector_type(8))) short;

// fp32 -> bf16 RNE
__device__ __forceinline__ short f2bf(float f) {
  union { float f; unsigned u; } v; v.f = f;
  unsigned r = v.u + 0x7fffu + ((v.u >> 16) & 1u);
  return (short)(r >> 16);
}

__device__ __forceinline__ void gload16(const void* g, void* l) {
  __builtin_amdgcn_global_load_lds(
      (const __attribute__((address_space(1))) unsigned int*)g,
      (__attribute__((address_space(3))) unsigned int*)l, 16, 0, 0);
}

__device__ __forceinline__ s8v pack8(float4 a, float4 b) {
  s8v p;
  p[0] = f2bf(a.x); p[1] = f2bf(a.y); p[2] = f2bf(a.z); p[3] = f2bf(a.w);
  p[4] = f2bf(b.x); p[5] = f2bf(b.y); p[6] = f2bf(b.z); p[7] = f2bf(b.w);
  return p;
}

__device__ __forceinline__ bfrag cvt8(f32x4 lo, f32x4 hi) {
  bfrag r;
  r[0] = (__bf16)lo[0]; r[1] = (__bf16)lo[1];
  r[2] = (__bf16)lo[2]; r[3] = (__bf16)lo[3];
  r[4] = (__bf16)hi[0]; r[5] = (__bf16)hi[1];
  r[6] = (__bf16)hi[2]; r[7] = (__bf16)hi[3];
  return r;
}

__global__ void k_zero(int* __restrict__ cursor) {
  if (threadIdx.x < NEXP) cursor[threadIdx.x] = 0;
}

// Fused: blocks 0..63 scatter tokens by expert; blocks 64..1087 convert
// weight fp32 -> bf16 (contiguous [E][O][I]).
__global__ void k_prep(const int* __restrict__ gate, int* __restrict__ cursor,
                       int* __restrict__ perm, const float* __restrict__ w,
                       s8v* __restrict__ wb) {
  __shared__ int lc[NEXP], lb[NEXP];
  const int bid = blockIdx.x, tid = threadIdx.x;
  if (bid < 64) {
    if (tid < NEXP) lc[tid] = 0;
    __syncthreads();
    int t = bid * 256 + tid;
    int e = gate[t];
    int ls = atomicAdd(&lc[e], 1);
    __syncthreads();
    if (tid < NEXP) lb[tid] = lc[tid] ? atomicAdd(&cursor[tid], lc[tid]) : 0;
    __syncthreads();
    perm[e * EROWS + lb[e] + ls] = t;
  } else {
    int idx = (bid - 64) * 256 + tid;
    const float4* src = (const float4*)w + (size_t)idx * 2;
    wb[idx] = pack8(src[0], src[1]);
  }
}

#define KBAR(N)                                                         \
  asm volatile("s_waitcnt vmcnt(" #N ") lgkmcnt(0)" ::: "memory");      \
  __builtin_amdgcn_sched_barrier(0);                                    \
  __builtin_amdgcn_s_barrier();                                         \
  __builtin_amdgcn_sched_barrier(0);

// Grouped GEMM, R5-proven homogeneous pipeline: BK=32, 3-slot ring, ALL
// staging via global_load_lds (6 ops/step: 4 fp32-A + 2 bf16-B), one
// counted barrier per step: KBAR(6) retires DMA(t+1) [2 COMPs of slack],
// DMA(t+2) rides across. A converted fp32->bf16 at fragment read (cvt8).
// Swizzles both-sides (rule #21): A clog=c^(row&7); B clog=c^((row^(row>>2))&3).
// XCD-affine grid: e=bid&7 -> XCD e; nt siblings 8 apart share A panel in L2.
__global__ __launch_bounds__(256, 2)
void moe_gemm4(const float* __restrict__ inp, const short* __restrict__ wbf,
               const int* __restrict__ cursor, const int* __restrict__ perm,
               float* __restrict__ out) {
  const int bid = blockIdx.x;
  const int e  = bid & 7;
  const int nt = (bid >> 3) & 3;
  const int mt = bid >> 5;
  const int cnt = cursor[e];
  if (mt * BM >= cnt) return;
  const int m_valid = min(BM, cnt - mt * BM);
  const int* pbase = perm + e * EROWS + mt * BM;

  __shared__ __align__(16) char lds[3 * SLOT];   // 72 KB ring
  __shared__ int toks[BM];

  const int tid = threadIdx.x;
  if (tid < BM) toks[tid] = pbase[(tid < m_valid) ? tid : 0];
  __syncthreads();

  const int lane = tid & 63;
  const int wid  = tid >> 6;
  const int wr = wid >> 1, wc = wid & 1;
  const int lr = lane & 15;
  const int lg = lane >> 4;

  // ---- A DMA geometry: 4 sites; phys chunk = s*256+tid -> row=s*32+(tid>>3),
  //      cphys=tid&7; source logical clog = cphys ^ (row&7)  (floats: clog*4)
  const float* agp[4];
#pragma unroll
  for (int s = 0; s < 4; s++) {
    int row  = s * 32 + (tid >> 3);
    int clog = (tid & 7) ^ (row & 7);
    agp[s] = inp + (size_t)toks[row] * INF + clog * 4;
  }

  // ---- B DMA geometry: 2 sites; phys chunk = s*256+tid -> row=s*64+(tid>>2),
  //      cphys=tid&3; clog = cphys ^ ((row^(row>>2))&3)  (shorts: clog*8)
  const short* Wbase = wbf + ((size_t)e * OUTF + (size_t)nt * BN) * INF;
  const short* bgp[2];
#pragma unroll
  for (int s = 0; s < 2; s++) {
    int row  = s * 64 + (tid >> 2);
    int clog = (tid & 3) ^ ((row ^ (row >> 2)) & 3);
    bgp[s] = Wbase + (size_t)row * INF + clog * 8;
  }

  f32x4 acc[4][4];
#pragma unroll
  for (int i = 0; i < 4; i++)
#pragma unroll
    for (int j = 0; j < 4; j++) acc[i][j] = (f32x4)0.0f;

#define DMA(slot_, t_)                                                        \
  {                                                                           \
    char* d_ = &lds[(slot_) * SLOT] + wid * 1024;                             \
    _Pragma("unroll") for (int s = 0; s < 4; s++)                             \
        gload16(agp[s] + (t_) * BK, d_ + s * 4096);                           \
    _Pragma("unroll") for (int s = 0; s < 2; s++)                             \
        gload16(bgp[s] + (t_) * BK, d_ + 16384 + s * 4096);                   \
  }
#define COMP(slot_)                                                           \
  {                                                                           \
    const char* Ab_ = &lds[(slot_) * SLOT];                                   \
    const char* Bb_ = Ab_ + 16384;                                            \
    bfrag af[4], bv[4];                                                       \
    _Pragma("unroll") for (int i = 0; i < 4; i++) {                           \
      int row = wr * 64 + i * 16 + lr;                                        \
      int c0 = (lg * 2) ^ (row & 7), c1 = (lg * 2 + 1) ^ (row & 7);           \
      f32x4 lo = *(const f32x4*)(Ab_ + row * 128 + c0 * 16);                  \
      f32x4 hi = *(const f32x4*)(Ab_ + row * 128 + c1 * 16);                  \
      af[i] = cvt8(lo, hi);                                                   \
    }                                                                         \
    _Pragma("unroll") for (int j = 0; j < 4; j++) {                           \
      int row = wc * 64 + j * 16 + lr;                                        \
      int c = lg ^ ((row ^ (row >> 2)) & 3);                                  \
      bv[j] = *(const bfrag*)(Bb_ + row * 64 + c * 16);                       \
    }                                                                         \
    _Pragma("unroll") for (int i = 0; i < 4; i++)                             \
      _Pragma("unroll") for (int j = 0; j < 4; j++)                           \
          acc[i][j] = __builtin_amdgcn_mfma_f32_16x16x32_bf16(                \
              af[i], bv[j], acc[i][j], 0, 0, 0);                              \
  }

  // ---- prologue: slots 0,1 in flight; retire slot 0
  DMA(0, 0);
  DMA(1, 1);
  KBAR(6)

#pragma unroll
  for (int t = 0; t < NS; t++) {
    if (t + 2 < NS) DMA((t + 2) % 3, t + 2);   // rides across the barrier
    COMP(t % 3);
    if (t + 2 < NS) {
      KBAR(6)      // retires DMA(t+1); DMA(t+2) stays in flight
    } else if (t + 1 < NS) {
      KBAR(0)      // drain DMA(NS-1)
    }
  }

  // ---- epilogue: C/D col=lane&15, row=(lane>>4)*4+reg (proven) ----
#pragma unroll
  for (int i = 0; i < 4; i++) {
    int rbase = wr * 64 + i * 16 + lg * 4;
#pragma unroll
    for (int r = 0; r < 4; r++) {
      int rr = rbase + r;
      if (rr < m_valid) {
        float* orow = out + (size_t)toks[rr] * OUTF + nt * BN + wc * 64 + lr;
#pragma unroll
        for (int j = 0; j < 4; j++) orow[j * 16] = acc[i][j][r];
      }
    }
  }
#undef DMA
#undef COMP
}

extern "C" void kernel_launch(void* const* d_in, const int* in_sizes, int n_in,
                              void* d_out, int out_size, void* d_ws, size_t ws_size,
                              hipStream_t stream) {
  (void)in_sizes; (void)n_in; (void)out_size; (void)ws_size;
  const float* inp    = (const float*)d_in[0];
  const int*   gate   = (const int*)d_in[1];
  const float* weight = (const float*)d_in[2];
  float* out = (float*)d_out;

  char* ws = (char*)d_ws;
  int*   cursor = (int*)ws;                    // 64 B
  int*   perm   = (int*)(ws + 4096);           // 8*5120*4 = 160 KB
  short* wbf    = (short*)(ws + (1 << 20));    // 4 MB bf16 weight

  k_zero<<<1, 64, 0, stream>>>(cursor);
  k_prep<<<64 + (NEXP * OUTF * INF) / (256 * 8), 256, 0, stream>>>(
      gate, cursor, perm, weight, (s8v*)wbf);
  moe_gemm4<<<NEXP * 4 * MAXMT, 256, 0, stream>>>(inp, wbf, cursor, perm, out);
}